// Round 3
// baseline (1485.605 us; speedup 1.0000x reference)
//
#include <hip/hip_runtime.h>

#define N_NODES 100000
#define N_EDGES 1600000
#define D 128

#define BN    128                 // nodes per bucket (dst >> 7)
#define NB    782                 // ceil(N_NODES / BN)
#define NBP   800                 // padded bucket-array stride
#define CHUNK 4096                // edges per k_part block (391 blocks)
#define SLOTS 12                  // LDS bin capacity in k_part (mean 5.2/bucket)
#define AST   132                 // acc tile stride in words (132 % 32 = 4)

#define XQ   (N_NODES * D / 4)    // x float4 quads = 3,200,000
#define XQB  (XQ / 256)           // 12500 blocks (exact)
#define WQ   (D * D / 4)          // 4096
#define WQB  (WQ / 256)           // 16 blocks (exact)
#define HB   256                  // histogram blocks (partial hists, no atomics)

typedef __bf16 bf16x8 __attribute__((ext_vector_type(8)));
typedef float  f32x4  __attribute__((ext_vector_type(4)));

static __device__ __forceinline__ unsigned short f2bf(float f) {
    union { float f; unsigned u; } v; v.f = f;
    unsigned r = v.u + 0x7FFFu + ((v.u >> 16) & 1u);   // RNE
    return (unsigned short)(r >> 16);
}
static __device__ __forceinline__ __bf16 bfbits(unsigned short s) {
    union { unsigned short u; __bf16 h; } v; v.u = s; return v.h;
}

// One edge: lane sl holds features 8sl..8sl+7 (bf16 pairs in u). Accumulate
// w * f into the permuted acc tile: feature c lives at col (c%8)*16 + c/8,
// so lane sl writes cols {fl*16 + sl} -> consecutive banks across the group.
static __device__ __forceinline__ void agg_edge(
    float* __restrict__ accs, const int2 p, const float4 u, const int sl)
{
    const float w = __int_as_float(p.y);
    const int ld = ((unsigned)p.x) >> 17;
    float* row = accs + ld * AST + sl;
    const unsigned qx = __float_as_uint(u.x);
    const unsigned qy = __float_as_uint(u.y);
    const unsigned qz = __float_as_uint(u.z);
    const unsigned qw = __float_as_uint(u.w);
    atomicAdd(row +   0, w * __uint_as_float(qx << 16));
    atomicAdd(row +  16, w * __uint_as_float(qx & 0xFFFF0000u));
    atomicAdd(row +  32, w * __uint_as_float(qy << 16));
    atomicAdd(row +  48, w * __uint_as_float(qy & 0xFFFF0000u));
    atomicAdd(row +  64, w * __uint_as_float(qz << 16));
    atomicAdd(row +  80, w * __uint_as_float(qz & 0xFFFF0000u));
    atomicAdd(row +  96, w * __uint_as_float(qw << 16));
    atomicAdd(row + 112, w * __uint_as_float(qw & 0xFFFF0000u));
}

// ---------------------------------------------------------------------------
// k_prep: fused coarse dst histogram (partial, atomic-free) | x->bf16 | W->bf16.
// bucket = dst >> 7 (no division).
// ---------------------------------------------------------------------------
__global__ __launch_bounds__(256) void k_prep(
    const float4* __restrict__ x4, ushort4* __restrict__ xh4,
    const float4* __restrict__ w4, ushort4* __restrict__ wh4,
    const int* __restrict__ ei, int* __restrict__ hpart)
{
    __shared__ int h[NBP];
    const int b = blockIdx.x;
    const int t = threadIdx.x;
    if (b < HB) {
        for (int c = t; c < NBP; c += 256) h[c] = 0;
        __syncthreads();
        for (int e = b * 256 + t; e < N_EDGES; e += HB * 256)
            atomicAdd(&h[ei[N_EDGES + e] >> 7], 1);
        __syncthreads();
        for (int c = t; c < NBP; c += 256) hpart[b * NBP + c] = h[c];
    } else if (b < HB + XQB) {
        const int i = (b - HB) * 256 + t;
        const float4 v = x4[i];
        xh4[i] = make_ushort4(f2bf(v.x), f2bf(v.y), f2bf(v.z), f2bf(v.w));
    } else {
        const int i = (b - HB - XQB) * 256 + t;
        const float4 v = w4[i];
        wh4[i] = make_ushort4(f2bf(v.x), f2bf(v.y), f2bf(v.z), f2bf(v.w));
    }
}

// Sum HB partial histograms then exclusive scan over NB buckets.
__global__ __launch_bounds__(1024) void k_cscan(
    const int* __restrict__ hpart, int* __restrict__ cOff, int* __restrict__ gcur)
{
    __shared__ int sh[1024];
    const int t = threadIdx.x;
    int v = 0;
    if (t < NB) {
        #pragma unroll 8
        for (int k = 0; k < HB; ++k) v += hpart[k * NBP + t];
    }
    sh[t] = v;
    __syncthreads();
    for (int d = 1; d < 1024; d <<= 1) {
        int u = (t >= d) ? sh[t - d] : 0;
        __syncthreads();
        sh[t] += u;
        __syncthreads();
    }
    if (t < NB) {
        const int excl = sh[t] - v;
        cOff[t] = excl;
        gcur[t] = excl;
    }
    if (t == NB - 1) cOff[NB] = sh[t];
}

// ---------------------------------------------------------------------------
// Partition edges into bucket regions with LDS binning so global writes land
// in contiguous runs. Pair packing: src | (local_dst<<17), ld = dst & 127.
// ---------------------------------------------------------------------------
__global__ __launch_bounds__(256, 1) void k_part(
    const int* __restrict__ ei, const float* __restrict__ ew,
    int* __restrict__ gcur, int2* __restrict__ part)
{
    __shared__ int2 bins[NB * SLOTS];   // 75 KB
    __shared__ int bcnt[NBP];
    __shared__ int bbase[NBP];
    const int t = threadIdx.x;
    const int e0 = blockIdx.x * CHUNK;

    for (int c = t; c < NBP; c += 256) bcnt[c] = 0;
    __syncthreads();

    #pragma unroll 8
    for (int k = 0; k < CHUNK / 256; ++k) {
        const int e = e0 + k * 256 + t;
        if (e < N_EDGES) {
            const int dst = ei[N_EDGES + e];
            const int src = ei[e];
            const int b = dst >> 7;
            const int ld = dst & 127;
            const int2 p = make_int2(src | (ld << 17), __float_as_int(ew[e]));
            const int r = atomicAdd(&bcnt[b], 1);
            if (r < SLOTS) bins[b * SLOTS + r] = p;
            else {
                int pos = atomicAdd(&gcur[b], 1);
                part[pos] = p;
            }
        }
    }
    __syncthreads();

    for (int c = t; c < NB; c += 256) {
        int c0 = min(bcnt[c], SLOTS);
        bbase[c] = c0 ? atomicAdd(&gcur[c], c0) : 0;
        bcnt[c] = c0;
    }
    __syncthreads();

    for (int s = t; s < NB * SLOTS; s += 256) {
        const int b = s / SLOTS;
        const int r = s - b * SLOTS;
        if (r < bcnt[b]) part[bbase[b] + r] = bins[s];
    }
}

// ---------------------------------------------------------------------------
// Fused streaming-aggregate + MFMA transform.
// Block = 512 threads = 32 groups of 16 lanes; owns one 128-node dst bucket
// as an LDS f32 tile [128][132] (66 KB, 2 blocks/CU = 16 waves/CU).
// Each group streams one edge per slot: full row load (16 lanes x float4 =
// 256 B), scale by w, ds_add_f32 into the permuted tile. 4-deep unroll ->
// 128 independent rows in flight per block: throughput-, not latency-bound.
// Then 8 waves x 16-row MFMA tiles: A read through the inverse permutation,
// B = wh, epilogue bias/prelu/relu.
// Layouts (verified m89/m91): A[m=lane&15][k=quad*8+j], B[n=lane&15][k=...],
// C: col=lane&15, row=quad*4+reg.
// ---------------------------------------------------------------------------
__global__ __launch_bounds__(512) void k_gx(
    const float4* __restrict__ xh4,        // bf16 x rows viewed as float4 (8 bf16)
    const int* __restrict__ cOff,
    const int2* __restrict__ pair,         // bucket-partitioned {src|ld<<17, w}
    const unsigned short* __restrict__ wh, // bf16 W [n][k]
    const float* __restrict__ bias, const float* __restrict__ pa,
    float* __restrict__ out)
{
    __shared__ float accs[BN * AST];       // 67,584 B

    const int tid = threadIdx.x;
    const int b = blockIdx.x;
    const int g = tid >> 4;                // 0..31
    const int sl = tid & 15;

    {
        const f32x4 z = {0.f, 0.f, 0.f, 0.f};
        for (int i = tid; i < BN * AST / 4; i += 512)
            ((f32x4*)accs)[i] = z;
    }
    __syncthreads();

    const int base = cOff[b];
    const int end = cOff[b + 1];

    int e = base + g;
    for (; e + 96 < end; e += 128) {
        const int2 p0 = pair[e +  0];
        const int2 p1 = pair[e + 32];
        const int2 p2 = pair[e + 64];
        const int2 p3 = pair[e + 96];
        const float4 u0 = xh4[(p0.x & 0x1FFFF) * 16 + sl];
        const float4 u1 = xh4[(p1.x & 0x1FFFF) * 16 + sl];
        const float4 u2 = xh4[(p2.x & 0x1FFFF) * 16 + sl];
        const float4 u3 = xh4[(p3.x & 0x1FFFF) * 16 + sl];
        agg_edge(accs, p0, u0, sl);
        agg_edge(accs, p1, u1, sl);
        agg_edge(accs, p2, u2, sl);
        agg_edge(accs, p3, u3, sl);
    }
    for (; e < end; e += 32) {
        const int2 p = pair[e];
        const float4 u = xh4[(p.x & 0x1FFFF) * 16 + sl];
        agg_edge(accs, p, u, sl);
    }
    __syncthreads();

    // ---- MFMA transform: 8 waves, one 16-row m-tile each ----
    const int lane = tid & 63;
    const int wv = tid >> 6;
    const int mm = lane & 15;
    const int q = lane >> 4;
    const float aP = pa[0];
    const int mbase = wv << 4;

    bf16x8 af[4];
    #pragma unroll
    for (int c = 0; c < 4; ++c) {
        const float* ap = accs + (mbase + mm) * AST + 4 * c + q;
        #pragma unroll
        for (int j = 0; j < 8; ++j)
            af[c][j] = bfbits(f2bf(ap[16 * j]));   // feature c*32+q*8+j
    }

    #pragma unroll
    for (int nt = 0; nt < 8; ++nt) {
        const int n = (nt << 4) + mm;
        f32x4 acc = {0.f, 0.f, 0.f, 0.f};
        #pragma unroll
        for (int c = 0; c < 4; ++c) {
            const bf16x8 bf = *(const bf16x8*)(wh + n * D + c * 32 + q * 8);
            acc = __builtin_amdgcn_mfma_f32_16x16x32_bf16(af[c], bf, acc, 0, 0, 0);
        }
        const float bv = bias[n];
        #pragma unroll
        for (int r = 0; r < 4; ++r) {
            const int node = b * BN + mbase + (q << 2) + r;
            if (node < N_NODES) {
                float v = acc[r] + bv;
                v = (v >= 0.f) ? v : aP * v;
                v = fmaxf(v, 0.f);
                out[(size_t)node * D + n] = v;
            }
        }
    }
}

// ---------------------------------------------------------------------------
// Tier-C fallbacks (tiny ws): atomic scatter + fp32 vector transform.
// ---------------------------------------------------------------------------
__global__ __launch_bounds__(256) void gcn_scatter(
    const float* __restrict__ x, const int* __restrict__ ei,
    const float* __restrict__ ew, float* __restrict__ agg)
{
    const int lane = threadIdx.x & 63;
    const int wave = (blockIdx.x * blockDim.x + threadIdx.x) >> 6;
    const int nwaves = (gridDim.x * blockDim.x) >> 6;
    for (int e = wave; e < N_EDGES; e += nwaves) {
        const int src = ei[e];
        const int dst = ei[N_EDGES + e];
        const float w = ew[e];
        const float2 v = ((const float2*)(x + (size_t)src * D))[lane];
        float* op = agg + (size_t)dst * D + lane * 2;
        unsafeAtomicAdd(op,     w * v.x);
        unsafeAtomicAdd(op + 1, w * v.y);
    }
}

#define MT 32
__global__ __launch_bounds__(256, 2) void gcn_transform(
    const float* __restrict__ A, const float* __restrict__ W,
    const float* __restrict__ bias, const float* __restrict__ pa,
    float* __restrict__ out)
{
    __shared__ float Wt[D][D];
    __shared__ float xs[MT][D];
    const int tid = threadIdx.x;
    const int row0 = blockIdx.x * MT;

    for (int j = tid; j < D * (D / 4); j += 256) {
        const int n = j & 127;
        const int kg = j >> 7;
        const float4 v = ((const float4*)W)[n * (D / 4) + kg];
        const int k4 = kg << 2;
        Wt[k4 + 0][n] = v.x; Wt[k4 + 1][n] = v.y;
        Wt[k4 + 2][n] = v.z; Wt[k4 + 3][n] = v.w;
    }
    for (int i = tid; i < MT * (D / 4); i += 256) {
        const int r = i >> 5;
        const int c4 = i & 31;
        ((float4*)xs[r])[c4] = ((const float4*)(A + (size_t)(row0 + r) * D))[c4];
    }
    __syncthreads();

    const int tn = tid & 31;
    const int tm = tid >> 5;
    float acc[4][4] = {};
    #pragma unroll
    for (int k = 0; k < D; k += 4) {
        const float4 wv0 = *(const float4*)&Wt[k + 0][tn * 4];
        const float4 wv1 = *(const float4*)&Wt[k + 1][tn * 4];
        const float4 wv2 = *(const float4*)&Wt[k + 2][tn * 4];
        const float4 wv3 = *(const float4*)&Wt[k + 3][tn * 4];
        #pragma unroll
        for (int i = 0; i < 4; ++i) {
            const float4 xv = *(const float4*)&xs[tm * 4 + i][k];
            acc[i][0] += xv.x * wv0.x + xv.y * wv1.x + xv.z * wv2.x + xv.w * wv3.x;
            acc[i][1] += xv.x * wv0.y + xv.y * wv1.y + xv.z * wv2.y + xv.w * wv3.y;
            acc[i][2] += xv.x * wv0.z + xv.y * wv1.z + xv.z * wv2.z + xv.w * wv3.z;
            acc[i][3] += xv.x * wv0.w + xv.y * wv1.w + xv.z * wv2.w + xv.w * wv3.w;
        }
    }
    const float a = pa[0];
    const float4 bv = ((const float4*)bias)[tn];
    #pragma unroll
    for (int i = 0; i < 4; ++i) {
        const int gr = row0 + tm * 4 + i;
        float t0 = acc[i][0] + bv.x, t1 = acc[i][1] + bv.y;
        float t2 = acc[i][2] + bv.z, t3 = acc[i][3] + bv.w;
        float4 r;
        r.x = fmaxf(t0 >= 0.f ? t0 : a * t0, 0.f);
        r.y = fmaxf(t1 >= 0.f ? t1 : a * t1, 0.f);
        r.z = fmaxf(t2 >= 0.f ? t2 : a * t2, 0.f);
        r.w = fmaxf(t3 >= 0.f ? t3 : a * t3, 0.f);
        ((float4*)(out + (size_t)gr * D))[tn] = r;
    }
}

// ---------------------------------------------------------------------------
extern "C" void kernel_launch(void* const* d_in, const int* in_sizes, int n_in,
                              void* d_out, int out_size, void* d_ws, size_t ws_size,
                              hipStream_t stream) {
    const float* x    = (const float*)d_in[0];
    const int*   ei   = (const int*)d_in[1];
    const float* ew   = (const float*)d_in[2];
    const float* W    = (const float*)d_in[3];
    const float* bias = (const float*)d_in[4];
    const float* pa   = (const float*)d_in[5];
    float* out = (float*)d_out;

    // Workspace layout (int units)
    const size_t o_cOff  = 0;                           // NB+1 = 783
    const size_t o_gcur  = 784;                         // NB = 782
    const size_t o_part  = 1568;                        // 8B-aligned; 2*N_EDGES ints
    const size_t o_wh    = o_part + 2 * (size_t)N_EDGES;     // 3,201,568 (16B-aligned)
    const size_t o_xh    = o_wh + (size_t)D * D / 2;         // 16B-aligned
    const size_t endA    = o_xh + (size_t)N_NODES * D / 2;
    const size_t needA   = endA * 4;

    int* wsb = (int*)d_ws;
    int* cOff  = wsb + o_cOff;
    int* gcur  = wsb + o_gcur;
    int2* part = (int2*)(wsb + o_part);
    unsigned short* wh = (unsigned short*)(wsb + o_wh);
    unsigned short* xh = (unsigned short*)(wsb + o_xh);
    int* hpart = (int*)part;   // HB*NBP ints (820 KB) scratch inside part region;
                               // dead before k_part writes part.

    if (ws_size >= needA) {
        k_prep <<<HB + XQB + WQB, 256, 0, stream>>>(
            (const float4*)x, (ushort4*)xh, (const float4*)W, (ushort4*)wh, ei, hpart);
        k_cscan<<<1, 1024, 0, stream>>>(hpart, cOff, gcur);
        k_part <<<(N_EDGES + CHUNK - 1) / CHUNK, 256, 0, stream>>>(ei, ew, gcur, part);
        k_gx   <<<NB, 512, 0, stream>>>(
            (const float4*)xh, cOff, part, wh, bias, pa, out);
    } else {
        (void)hipMemsetAsync(out, 0, (size_t)N_NODES * D * sizeof(float), stream);
        gcn_scatter<<<12800, 256, 0, stream>>>(x, ei, ew, out);
        gcn_transform<<<N_NODES / MT, 256, 0, stream>>>(out, W, bias, pa, out);
    }
}

// Round 4
// 603.400 us; speedup vs baseline: 2.4621x; 2.4621x over previous
//
#include <hip/hip_runtime.h>

#define N_NODES 100000
#define N_EDGES 1600000
#define D 128

#define XQ   (N_NODES * D / 4)    // x float4 quads = 3,200,000
#define XQB  (XQ / 256)           // 12500 blocks (exact)
#define WQ   (D * D / 4)          // 4096
#define WQB  (WQ / 256)           // 16 blocks (exact)
#define HB   256                  // degree-histogram blocks

typedef __bf16 bf16x8 __attribute__((ext_vector_type(8)));
typedef float  f32x4  __attribute__((ext_vector_type(4)));
typedef unsigned short u16x8 __attribute__((ext_vector_type(8)));

static __device__ __forceinline__ unsigned short f2bf(float f) {
    union { float f; unsigned u; } v; v.f = f;
    unsigned r = v.u + 0x7FFFu + ((v.u >> 16) & 1u);   // RNE
    return (unsigned short)(r >> 16);
}

// Accumulate one gathered bf16x8 row (as float4 bits) scaled by wt.
static __device__ __forceinline__ void accum_row(
    float4& acc0, float4& acc1, const float4 u, const float wt)
{
    const unsigned qx = __float_as_uint(u.x);
    const unsigned qy = __float_as_uint(u.y);
    const unsigned qz = __float_as_uint(u.z);
    const unsigned qw = __float_as_uint(u.w);
    acc0.x += wt * __uint_as_float(qx << 16);
    acc0.y += wt * __uint_as_float(qx & 0xFFFF0000u);
    acc0.z += wt * __uint_as_float(qy << 16);
    acc0.w += wt * __uint_as_float(qy & 0xFFFF0000u);
    acc1.x += wt * __uint_as_float(qz << 16);
    acc1.y += wt * __uint_as_float(qz & 0xFFFF0000u);
    acc1.z += wt * __uint_as_float(qw << 16);
    acc1.w += wt * __uint_as_float(qw & 0xFFFF0000u);
}

// ---------------------------------------------------------------------------
// k_prep: fused per-node degree count | x->bf16 cast | W->bf16 cast.
// Degree blocks FIRST so their latency overlaps the BW-heavy cast blocks.
// deg[] (100K ints, L2-resident) via direct global atomics: 1.6M adds over
// 100K addresses = ~16 per counter, negligible contention.
// ---------------------------------------------------------------------------
__global__ __launch_bounds__(256) void k_prep(
    const float4* __restrict__ x4, ushort4* __restrict__ xh4,
    const float4* __restrict__ w4, ushort4* __restrict__ wh4,
    const int* __restrict__ ei, int* __restrict__ deg)
{
    const int b = blockIdx.x;
    const int t = threadIdx.x;
    if (b < HB) {
        for (int e = b * 256 + t; e < N_EDGES; e += HB * 256)
            atomicAdd(&deg[ei[N_EDGES + e]], 1);
    } else if (b < HB + XQB) {
        const int i = (b - HB) * 256 + t;
        const float4 v = x4[i];
        xh4[i] = make_ushort4(f2bf(v.x), f2bf(v.y), f2bf(v.z), f2bf(v.w));
    } else {
        const int i = (b - HB - XQB) * 256 + t;
        const float4 v = w4[i];
        wh4[i] = make_ushort4(f2bf(v.x), f2bf(v.y), f2bf(v.z), f2bf(v.w));
    }
}

// ---------------------------------------------------------------------------
// Single-block scan of 100K degrees -> off[] (CSR offsets) + cur[] (cursors).
// 1024 threads x 98-node serial chunks; Hillis-Steele over the 1024 partials.
// ---------------------------------------------------------------------------
#define SCHUNK 98
__global__ __launch_bounds__(1024) void k_scan(
    const int* __restrict__ deg, int* __restrict__ off, int* __restrict__ cur)
{
    __shared__ int sh[1024];
    const int t = threadIdx.x;
    const int lo = t * SCHUNK;
    const int hi = min(lo + SCHUNK, N_NODES);
    int s = 0;
    for (int i = lo; i < hi; ++i) s += deg[i];
    sh[t] = s;
    __syncthreads();
    for (int d = 1; d < 1024; d <<= 1) {
        int u = (t >= d) ? sh[t - d] : 0;
        __syncthreads();
        sh[t] += u;
        __syncthreads();
    }
    int running = sh[t] - s;     // exclusive base for this chunk
    for (int i = lo; i < hi; ++i) {
        const int dv = deg[i];
        off[i] = running;
        cur[i] = running;
        running += dv;
    }
    if (t == 1023) off[N_NODES] = sh[1023];
}

// ---------------------------------------------------------------------------
// Scatter edges into CSR slots: pos = atomicAdd(cur[dst]); part[pos]={src,w}.
// part (12.8 MB) is L2-absorbed; reads fully coalesced.
// ---------------------------------------------------------------------------
__global__ __launch_bounds__(256) void k_scat(
    const int* __restrict__ ei, const float* __restrict__ ew,
    int* __restrict__ cur, int2* __restrict__ part)
{
    const int e = blockIdx.x * 256 + threadIdx.x;
    if (e < N_EDGES) {
        const int src = ei[e];
        const int dst = ei[N_EDGES + e];
        const int pos = atomicAdd(&cur[dst], 1);
        part[pos] = make_int2(src, __float_as_int(ew[e]));
    }
}

// ---------------------------------------------------------------------------
// Fused gather + MFMA transform: out = relu(prelu((A x)_tile @ W^T + b, a)).
// (identical to the verified 106-us round-2 version)
// Block = 4 waves = 16 nodes. Gather: QUARTER-wave edge grouping; the 4
// 16-lane groups fetch DIFFERENT edges' rows at 16B/lane (float4 = 8 bf16):
// 4 edges per issue slot, 16 rows in flight at 4-deep unroll. Folded rows go
// to a bf16 LDS tile [16][136]; MFMA loads A fragments directly as bf16x8.
// Layouts (verified m89/m91): A[m=lane&15][k=quad*8+j], B[n=lane&15][k=...],
// C: col=lane&15, row=quad*4+reg.
// ---------------------------------------------------------------------------
__global__ __launch_bounds__(256) void k_gx(
    const float4* __restrict__ xh4,        // bf16 x rows viewed as float4 (8 bf16)
    const int* __restrict__ off,
    const int2* __restrict__ pair,         // CSR {src, w}
    const unsigned short* __restrict__ wh, // bf16 W [n][k]
    const float* __restrict__ bias, const float* __restrict__ pa,
    float* __restrict__ out)
{
    __shared__ unsigned short tb[16][136]; // bf16 tile, stride 272B

    const int tid = threadIdx.x;
    const int wv = tid >> 6;
    const int lane = tid & 63;
    const int grp = lane >> 4;             // 0..3: which edge of the 4-group
    const int sl = lane & 15;              // feature chunk: 8 bf16 at 8*sl
    const int m0 = blockIdx.x << 4;
    const float aP = pa[0];

    // ---- gather: 4 nodes per wave, 4 edges per issue slot (one per group) ----
    for (int j = 0; j < 4; ++j) {
        const int r = (wv << 2) + j;
        const int n = m0 + r;
        const int beg = off[n], end = off[n + 1];
        float4 acc0 = make_float4(0.f, 0.f, 0.f, 0.f);
        float4 acc1 = make_float4(0.f, 0.f, 0.f, 0.f);

        int e = beg + grp;
        for (; e + 12 < end; e += 16) {
            const int2 p0 = pair[e + 0], p1 = pair[e + 4];
            const int2 p2 = pair[e + 8], p3 = pair[e + 12];
            const float4 u0 = xh4[p0.x * 16 + sl];
            const float4 u1 = xh4[p1.x * 16 + sl];
            const float4 u2 = xh4[p2.x * 16 + sl];
            const float4 u3 = xh4[p3.x * 16 + sl];
            accum_row(acc0, acc1, u0, __int_as_float(p0.y));
            accum_row(acc0, acc1, u1, __int_as_float(p1.y));
            accum_row(acc0, acc1, u2, __int_as_float(p2.y));
            accum_row(acc0, acc1, u3, __int_as_float(p3.y));
        }
        for (; e < end; e += 4) {
            const int2 p = pair[e];
            const float4 u = xh4[p.x * 16 + sl];
            accum_row(acc0, acc1, u, __int_as_float(p.y));
        }
        // fold groups 1..3 into group 0
        acc0.x += __shfl_down(acc0.x, 16, 64); acc0.y += __shfl_down(acc0.y, 16, 64);
        acc0.z += __shfl_down(acc0.z, 16, 64); acc0.w += __shfl_down(acc0.w, 16, 64);
        acc1.x += __shfl_down(acc1.x, 16, 64); acc1.y += __shfl_down(acc1.y, 16, 64);
        acc1.z += __shfl_down(acc1.z, 16, 64); acc1.w += __shfl_down(acc1.w, 16, 64);
        acc0.x += __shfl_down(acc0.x, 32, 64); acc0.y += __shfl_down(acc0.y, 32, 64);
        acc0.z += __shfl_down(acc0.z, 32, 64); acc0.w += __shfl_down(acc0.w, 32, 64);
        acc1.x += __shfl_down(acc1.x, 32, 64); acc1.y += __shfl_down(acc1.y, 32, 64);
        acc1.z += __shfl_down(acc1.z, 32, 64); acc1.w += __shfl_down(acc1.w, 32, 64);
        if (grp == 0) {
            u16x8 s;
            s[0] = f2bf(acc0.x); s[1] = f2bf(acc0.y);
            s[2] = f2bf(acc0.z); s[3] = f2bf(acc0.w);
            s[4] = f2bf(acc1.x); s[5] = f2bf(acc1.y);
            s[6] = f2bf(acc1.z); s[7] = f2bf(acc1.w);
            *(u16x8*)&tb[r][sl * 8] = s;   // features 8sl..8sl+7, 16B aligned
        }
    }
    __syncthreads();

    // ---- MFMA transform on the 16-row bf16 tile ----
    const int mm = lane & 15;
    const int quad = lane >> 4;

    bf16x8 af[4];
    #pragma unroll
    for (int c = 0; c < 4; ++c)
        af[c] = *(const bf16x8*)&tb[mm][c * 32 + quad * 8];

    #pragma unroll
    for (int t = 0; t < 2; ++t) {
        const int n = ((wv * 2 + t) << 4) + mm;
        f32x4 acc = {0.f, 0.f, 0.f, 0.f};
        #pragma unroll
        for (int c = 0; c < 4; ++c) {
            const bf16x8 bf = *(const bf16x8*)(wh + n * D + c * 32 + quad * 8);
            acc = __builtin_amdgcn_mfma_f32_16x16x32_bf16(af[c], bf, acc, 0, 0, 0);
        }
        const float bv = bias[n];
        #pragma unroll
        for (int r = 0; r < 4; ++r) {
            float v = acc[r] + bv;
            v = (v >= 0.f) ? v : aP * v;
            v = fmaxf(v, 0.f);
            out[(size_t)(m0 + (quad << 2) + r) * D + n] = v;
        }
    }
}

// ---------------------------------------------------------------------------
// Tier-C fallbacks (tiny ws): atomic scatter + fp32 vector transform.
// ---------------------------------------------------------------------------
__global__ __launch_bounds__(256) void gcn_scatter(
    const float* __restrict__ x, const int* __restrict__ ei,
    const float* __restrict__ ew, float* __restrict__ agg)
{
    const int lane = threadIdx.x & 63;
    const int wave = (blockIdx.x * blockDim.x + threadIdx.x) >> 6;
    const int nwaves = (gridDim.x * blockDim.x) >> 6;
    for (int e = wave; e < N_EDGES; e += nwaves) {
        const int src = ei[e];
        const int dst = ei[N_EDGES + e];
        const float w = ew[e];
        const float2 v = ((const float2*)(x + (size_t)src * D))[lane];
        float* op = agg + (size_t)dst * D + lane * 2;
        unsafeAtomicAdd(op,     w * v.x);
        unsafeAtomicAdd(op + 1, w * v.y);
    }
}

#define MT 32
__global__ __launch_bounds__(256, 2) void gcn_transform(
    const float* __restrict__ A, const float* __restrict__ W,
    const float* __restrict__ bias, const float* __restrict__ pa,
    float* __restrict__ out)
{
    __shared__ float Wt[D][D];
    __shared__ float xs[MT][D];
    const int tid = threadIdx.x;
    const int row0 = blockIdx.x * MT;

    for (int j = tid; j < D * (D / 4); j += 256) {
        const int n = j & 127;
        const int kg = j >> 7;
        const float4 v = ((const float4*)W)[n * (D / 4) + kg];
        const int k4 = kg << 2;
        Wt[k4 + 0][n] = v.x; Wt[k4 + 1][n] = v.y;
        Wt[k4 + 2][n] = v.z; Wt[k4 + 3][n] = v.w;
    }
    for (int i = tid; i < MT * (D / 4); i += 256) {
        const int r = i >> 5;
        const int c4 = i & 31;
        ((float4*)xs[r])[c4] = ((const float4*)(A + (size_t)(row0 + r) * D))[c4];
    }
    __syncthreads();

    const int tn = tid & 31;
    const int tm = tid >> 5;
    float acc[4][4] = {};
    #pragma unroll
    for (int k = 0; k < D; k += 4) {
        const float4 wv0 = *(const float4*)&Wt[k + 0][tn * 4];
        const float4 wv1 = *(const float4*)&Wt[k + 1][tn * 4];
        const float4 wv2 = *(const float4*)&Wt[k + 2][tn * 4];
        const float4 wv3 = *(const float4*)&Wt[k + 3][tn * 4];
        #pragma unroll
        for (int i = 0; i < 4; ++i) {
            const float4 xv = *(const float4*)&xs[tm * 4 + i][k];
            acc[i][0] += xv.x * wv0.x + xv.y * wv1.x + xv.z * wv2.x + xv.w * wv3.x;
            acc[i][1] += xv.x * wv0.y + xv.y * wv1.y + xv.z * wv2.y + xv.w * wv3.y;
            acc[i][2] += xv.x * wv0.z + xv.y * wv1.z + xv.z * wv2.z + xv.w * wv3.z;
            acc[i][3] += xv.x * wv0.w + xv.y * wv1.w + xv.z * wv2.w + xv.w * wv3.w;
        }
    }
    const float a = pa[0];
    const float4 bv = ((const float4*)bias)[tn];
    #pragma unroll
    for (int i = 0; i < 4; ++i) {
        const int gr = row0 + tm * 4 + i;
        float t0 = acc[i][0] + bv.x, t1 = acc[i][1] + bv.y;
        float t2 = acc[i][2] + bv.z, t3 = acc[i][3] + bv.w;
        float4 r;
        r.x = fmaxf(t0 >= 0.f ? t0 : a * t0, 0.f);
        r.y = fmaxf(t1 >= 0.f ? t1 : a * t1, 0.f);
        r.z = fmaxf(t2 >= 0.f ? t2 : a * t2, 0.f);
        r.w = fmaxf(t3 >= 0.f ? t3 : a * t3, 0.f);
        ((float4*)(out + (size_t)gr * D))[tn] = r;
    }
}

// ---------------------------------------------------------------------------
extern "C" void kernel_launch(void* const* d_in, const int* in_sizes, int n_in,
                              void* d_out, int out_size, void* d_ws, size_t ws_size,
                              hipStream_t stream) {
    const float* x    = (const float*)d_in[0];
    const int*   ei   = (const int*)d_in[1];
    const float* ew   = (const float*)d_in[2];
    const float* W    = (const float*)d_in[3];
    const float* bias = (const float*)d_in[4];
    const float* pa   = (const float*)d_in[5];
    float* out = (float*)d_out;

    // Workspace layout (int units)
    const size_t o_off   = 0;                                 // N_NODES+1
    const size_t o_cur   = 100004;                            // N_NODES
    const size_t o_part  = 200004;                            // 2*N_EDGES (int2-aligned)
    const size_t o_wh    = o_part + 2 * (size_t)N_EDGES;      // 3,400,004 (16B-aligned)
    const size_t o_xh    = o_wh + (size_t)D * D / 2;          // 3,408,196 (16B-aligned)
    const size_t endA    = o_xh + (size_t)N_NODES * D / 2;    // 9,808,196
    const size_t needA   = endA * 4;

    int* wsb = (int*)d_ws;
    int* off   = wsb + o_off;
    int* cur   = wsb + o_cur;
    int2* part = (int2*)(wsb + o_part);
    unsigned short* wh = (unsigned short*)(wsb + o_wh);
    unsigned short* xh = (unsigned short*)(wsb + o_xh);
    int* deg = (int*)part;     // 100K ints scratch inside part region;
                               // consumed by k_scan before k_scat writes part.

    if (ws_size >= needA) {
        (void)hipMemsetAsync(deg, 0, N_NODES * sizeof(int), stream);
        k_prep <<<HB + XQB + WQB, 256, 0, stream>>>(
            (const float4*)x, (ushort4*)xh, (const float4*)W, (ushort4*)wh, ei, deg);
        k_scan <<<1, 1024, 0, stream>>>(deg, off, cur);
        k_scat <<<(N_EDGES + 255) / 256, 256, 0, stream>>>(ei, ew, cur, part);
        k_gx   <<<N_NODES / 16, 256, 0, stream>>>(
            (const float4*)xh, off, part, wh, bias, pa, out);
    } else {
        (void)hipMemsetAsync(out, 0, (size_t)N_NODES * D * sizeof(float), stream);
        gcn_scatter<<<12800, 256, 0, stream>>>(x, ei, ew, out);
        gcn_transform<<<N_NODES / MT, 256, 0, stream>>>(out, W, bias, pa, out);
    }
}

// Round 5
// 276.486 us; speedup vs baseline: 5.3732x; 2.1824x over previous
//
#include <hip/hip_runtime.h>

#define N_NODES 100000
#define N_EDGES 1600000
#define D 128

#define NCB   512                 // coarse buckets
#define BR    196                 // nodes per coarse bucket
#define CHUNK 8192                // edges per k_part block (196 blocks = 1 round)
#define SLOTS 24                  // LDS bin capacity in k_part
#define CAP   6144                // max pairs per coarse bucket in k_csr

#define XQ   (N_NODES * D / 4)    // x float4 quads = 3,200,000
#define XQB  (XQ / 256)           // 12500 blocks (exact)
#define WQ   (D * D / 4)          // 4096
#define WQB  (WQ / 256)           // 16 blocks (exact)
#define HB   256                  // histogram blocks

typedef __bf16 bf16x8 __attribute__((ext_vector_type(8)));
typedef float  f32x4  __attribute__((ext_vector_type(4)));
typedef unsigned short u16x8 __attribute__((ext_vector_type(8)));

static __device__ __forceinline__ unsigned short f2bf(float f) {
    union { float f; unsigned u; } v; v.f = f;
    unsigned r = v.u + 0x7FFFu + ((v.u >> 16) & 1u);   // RNE
    return (unsigned short)(r >> 16);
}

// Accumulate one gathered bf16x8 row (as float4 bits) scaled by wt.
static __device__ __forceinline__ void accum_row(
    float4& acc0, float4& acc1, const float4 u, const float wt)
{
    const unsigned qx = __float_as_uint(u.x);
    const unsigned qy = __float_as_uint(u.y);
    const unsigned qz = __float_as_uint(u.z);
    const unsigned qw = __float_as_uint(u.w);
    acc0.x += wt * __uint_as_float(qx << 16);
    acc0.y += wt * __uint_as_float(qx & 0xFFFF0000u);
    acc0.z += wt * __uint_as_float(qy << 16);
    acc0.w += wt * __uint_as_float(qy & 0xFFFF0000u);
    acc1.x += wt * __uint_as_float(qz << 16);
    acc1.y += wt * __uint_as_float(qz & 0xFFFF0000u);
    acc1.z += wt * __uint_as_float(qw << 16);
    acc1.w += wt * __uint_as_float(qw & 0xFFFF0000u);
}

// ---------------------------------------------------------------------------
// k_prep: fused coarse dst histogram | x->bf16 cast | W->bf16 cast.
// Hist blocks FIRST (overlap the BW-heavy casts). Each hist block builds an
// LDS histogram then merges with 512 global atomics -> ghist is FULLY REDUCED
// when k_cscan runs (131K atomics over 512 addrs = negligible; the round-2/4
// "partial histogram + serial sum" alternative was a 90-230us latency trap).
// ---------------------------------------------------------------------------
__global__ __launch_bounds__(256) void k_prep(
    const float4* __restrict__ x4, ushort4* __restrict__ xh4,
    const float4* __restrict__ w4, ushort4* __restrict__ wh4,
    const int* __restrict__ ei, int* __restrict__ ghist)
{
    __shared__ int h[NCB];
    const int b = blockIdx.x;
    const int t = threadIdx.x;
    if (b < HB) {
        h[t] = 0; h[t + 256] = 0;
        __syncthreads();
        for (int e = b * 256 + t; e < N_EDGES; e += HB * 256)
            atomicAdd(&h[ei[N_EDGES + e] / BR], 1);
        __syncthreads();
        atomicAdd(&ghist[t], h[t]);
        atomicAdd(&ghist[t + 256], h[t + 256]);
    } else if (b < HB + XQB) {
        const int i = (b - HB) * 256 + t;
        const float4 v = x4[i];
        xh4[i] = make_ushort4(f2bf(v.x), f2bf(v.y), f2bf(v.z), f2bf(v.w));
    } else {
        const int i = (b - HB - XQB) * 256 + t;
        const float4 v = w4[i];
        wh4[i] = make_ushort4(f2bf(v.x), f2bf(v.y), f2bf(v.z), f2bf(v.w));
    }
}

// Exclusive scan of the reduced 512-entry histogram: ONE load per thread.
__global__ __launch_bounds__(512) void k_cscan(
    const int* __restrict__ ghist, int* __restrict__ cOff, int* __restrict__ gcur)
{
    __shared__ int sh[NCB];
    const int t = threadIdx.x;
    const int v = ghist[t];
    sh[t] = v;
    __syncthreads();
    for (int d = 1; d < NCB; d <<= 1) {
        int u = (t >= d) ? sh[t - d] : 0;
        __syncthreads();
        sh[t] += u;
        __syncthreads();
    }
    const int excl = sh[t] - v;
    cOff[t] = excl;
    gcur[t] = excl;
    if (t == NCB - 1) cOff[NCB] = sh[NCB - 1];
}

// ---------------------------------------------------------------------------
// Pass 1: partition edges into coarse-bucket regions with LDS binning so
// global writes land in contiguous runs. Pair packing: src | (local_dst<<17).
// CHUNK=8192 -> 196 blocks (single round at 1 block/CU).
// ---------------------------------------------------------------------------
__global__ __launch_bounds__(256, 1) void k_part(
    const int* __restrict__ ei, const float* __restrict__ ew,
    int* __restrict__ gcur, int2* __restrict__ part)
{
    __shared__ int2 bins[NCB * SLOTS];   // 96 KB
    __shared__ int bcnt[NCB];
    __shared__ int bbase[NCB];
    const int t = threadIdx.x;
    const int e0 = blockIdx.x * CHUNK;

    bcnt[t] = 0; bcnt[t + 256] = 0;
    __syncthreads();

    #pragma unroll 8
    for (int k = 0; k < CHUNK / 256; ++k) {
        const int e = e0 + k * 256 + t;
        if (e < N_EDGES) {
            const int dst = ei[N_EDGES + e];
            const int src = ei[e];
            const int b = dst / BR;
            const int ld = dst - b * BR;
            const int2 p = make_int2(src | (ld << 17), __float_as_int(ew[e]));
            const int r = atomicAdd(&bcnt[b], 1);
            if (r < SLOTS) bins[b * SLOTS + r] = p;
            else {
                int pos = atomicAdd(&gcur[b], 1);
                part[pos] = p;
            }
        }
    }
    __syncthreads();

    {
        int c0 = min(bcnt[t], SLOTS);
        int c1 = min(bcnt[t + 256], SLOTS);
        bbase[t]       = c0 ? atomicAdd(&gcur[t], c0) : 0;
        bbase[t + 256] = c1 ? atomicAdd(&gcur[t + 256], c1) : 0;
        bcnt[t] = c0; bcnt[t + 256] = c1;
    }
    __syncthreads();

    for (int s = t; s < NCB * SLOTS; s += 256) {
        const int b = s / SLOTS;
        const int r = s - b * SLOTS;
        if (r < bcnt[b]) part[bbase[b] + r] = bins[s];
    }
}

// ---------------------------------------------------------------------------
// Pass 2: per-bucket LDS sort -> in-place CSR + off[]. No obuf: reorder
// scatters directly to global (region is L2-hot; all reads complete before
// the barrier). LDS 51 KB -> 3 blocks/CU.
// ---------------------------------------------------------------------------
__global__ __launch_bounds__(256) void k_csr(
    const int* __restrict__ cOff, int2* __restrict__ part, int* __restrict__ off)
{
    __shared__ int2 buf[CAP];    // 48 KB
    __shared__ int nh[256];
    __shared__ int orig[256];
    __shared__ int cur[256];

    const int b = blockIdx.x;
    const int t = threadIdx.x;
    const int lo = b * BR;
    const int base = cOff[b];
    int cnt = cOff[b + 1] - base;
    if (cnt > CAP) cnt = CAP;    // unreachable statistically; guards LDS

    nh[t] = 0;
    __syncthreads();

    for (int i = t; i < cnt; i += 256) {
        const int2 p = part[base + i];
        buf[i] = p;
        atomicAdd(&nh[((unsigned)p.x) >> 17], 1);
    }
    __syncthreads();
    orig[t] = nh[t];
    __syncthreads();
    for (int d = 1; d < 256; d <<= 1) {
        int u = (t >= d) ? nh[t - d] : 0;
        __syncthreads();
        nh[t] += u;
        __syncthreads();
    }
    const int excl = nh[t] - orig[t];
    cur[t] = excl;
    if (t < BR && lo + t < N_NODES) off[lo + t] = base + excl;
    if (b == NCB - 1 && t == 0) off[N_NODES] = cOff[NCB];
    __syncthreads();

    for (int i = t; i < cnt; i += 256) {
        const int2 p = buf[i];
        const int ld = ((unsigned)p.x) >> 17;
        const int r = atomicAdd(&cur[ld], 1);
        part[base + r] = make_int2(p.x & 0x1FFFF, p.y);
    }
}

// ---------------------------------------------------------------------------
// Fused gather + MFMA transform: out = relu(prelu((A x)_tile @ W^T + b, a)).
// (identical to the verified 106-us round-2 version)
// Block = 4 waves = 16 nodes. Gather: QUARTER-wave edge grouping; the 4
// 16-lane groups fetch DIFFERENT edges' rows at 16B/lane (float4 = 8 bf16):
// 4 edges per issue slot, 16 rows in flight at 4-deep unroll. Folded rows go
// to a bf16 LDS tile [16][136]; MFMA loads A fragments directly as bf16x8.
// Layouts (verified m89/m91): A[m=lane&15][k=quad*8+j], B[n=lane&15][k=...],
// C: col=lane&15, row=quad*4+reg.
// ---------------------------------------------------------------------------
__global__ __launch_bounds__(256) void k_gx(
    const float4* __restrict__ xh4,        // bf16 x rows viewed as float4 (8 bf16)
    const int* __restrict__ off,
    const int2* __restrict__ pair,         // CSR {src, w}
    const unsigned short* __restrict__ wh, // bf16 W [n][k]
    const float* __restrict__ bias, const float* __restrict__ pa,
    float* __restrict__ out)
{
    __shared__ unsigned short tb[16][136]; // bf16 tile, stride 272B

    const int tid = threadIdx.x;
    const int wv = tid >> 6;
    const int lane = tid & 63;
    const int grp = lane >> 4;             // 0..3: which edge of the 4-group
    const int sl = lane & 15;              // feature chunk: 8 bf16 at 8*sl
    const int m0 = blockIdx.x << 4;
    const float aP = pa[0];

    // ---- gather: 4 nodes per wave, 4 edges per issue slot (one per group) ----
    for (int j = 0; j < 4; ++j) {
        const int r = (wv << 2) + j;
        const int n = m0 + r;
        const int beg = off[n], end = off[n + 1];
        float4 acc0 = make_float4(0.f, 0.f, 0.f, 0.f);
        float4 acc1 = make_float4(0.f, 0.f, 0.f, 0.f);

        int e = beg + grp;
        for (; e + 12 < end; e += 16) {
            const int2 p0 = pair[e + 0], p1 = pair[e + 4];
            const int2 p2 = pair[e + 8], p3 = pair[e + 12];
            const float4 u0 = xh4[p0.x * 16 + sl];
            const float4 u1 = xh4[p1.x * 16 + sl];
            const float4 u2 = xh4[p2.x * 16 + sl];
            const float4 u3 = xh4[p3.x * 16 + sl];
            accum_row(acc0, acc1, u0, __int_as_float(p0.y));
            accum_row(acc0, acc1, u1, __int_as_float(p1.y));
            accum_row(acc0, acc1, u2, __int_as_float(p2.y));
            accum_row(acc0, acc1, u3, __int_as_float(p3.y));
        }
        for (; e < end; e += 4) {
            const int2 p = pair[e];
            const float4 u = xh4[p.x * 16 + sl];
            accum_row(acc0, acc1, u, __int_as_float(p.y));
        }
        // fold groups 1..3 into group 0
        acc0.x += __shfl_down(acc0.x, 16, 64); acc0.y += __shfl_down(acc0.y, 16, 64);
        acc0.z += __shfl_down(acc0.z, 16, 64); acc0.w += __shfl_down(acc0.w, 16, 64);
        acc1.x += __shfl_down(acc1.x, 16, 64); acc1.y += __shfl_down(acc1.y, 16, 64);
        acc1.z += __shfl_down(acc1.z, 16, 64); acc1.w += __shfl_down(acc1.w, 16, 64);
        acc0.x += __shfl_down(acc0.x, 32, 64); acc0.y += __shfl_down(acc0.y, 32, 64);
        acc0.z += __shfl_down(acc0.z, 32, 64); acc0.w += __shfl_down(acc0.w, 32, 64);
        acc1.x += __shfl_down(acc1.x, 32, 64); acc1.y += __shfl_down(acc1.y, 32, 64);
        acc1.z += __shfl_down(acc1.z, 32, 64); acc1.w += __shfl_down(acc1.w, 32, 64);
        if (grp == 0) {
            u16x8 s;
            s[0] = f2bf(acc0.x); s[1] = f2bf(acc0.y);
            s[2] = f2bf(acc0.z); s[3] = f2bf(acc0.w);
            s[4] = f2bf(acc1.x); s[5] = f2bf(acc1.y);
            s[6] = f2bf(acc1.z); s[7] = f2bf(acc1.w);
            *(u16x8*)&tb[r][sl * 8] = s;   // features 8sl..8sl+7, 16B aligned
        }
    }
    __syncthreads();

    // ---- MFMA transform on the 16-row bf16 tile ----
    const int mm = lane & 15;
    const int quad = lane >> 4;

    bf16x8 af[4];
    #pragma unroll
    for (int c = 0; c < 4; ++c)
        af[c] = *(const bf16x8*)&tb[mm][c * 32 + quad * 8];

    #pragma unroll
    for (int t = 0; t < 2; ++t) {
        const int n = ((wv * 2 + t) << 4) + mm;
        f32x4 acc = {0.f, 0.f, 0.f, 0.f};
        #pragma unroll
        for (int c = 0; c < 4; ++c) {
            const bf16x8 bf = *(const bf16x8*)(wh + n * D + c * 32 + quad * 8);
            acc = __builtin_amdgcn_mfma_f32_16x16x32_bf16(af[c], bf, acc, 0, 0, 0);
        }
        const float bv = bias[n];
        #pragma unroll
        for (int r = 0; r < 4; ++r) {
            float v = acc[r] + bv;
            v = (v >= 0.f) ? v : aP * v;
            v = fmaxf(v, 0.f);
            out[(size_t)(m0 + (quad << 2) + r) * D + n] = v;
        }
    }
}

// ---------------------------------------------------------------------------
// Tier-C fallbacks (tiny ws): atomic scatter + fp32 vector transform.
// ---------------------------------------------------------------------------
__global__ __launch_bounds__(256) void gcn_scatter(
    const float* __restrict__ x, const int* __restrict__ ei,
    const float* __restrict__ ew, float* __restrict__ agg)
{
    const int lane = threadIdx.x & 63;
    const int wave = (blockIdx.x * blockDim.x + threadIdx.x) >> 6;
    const int nwaves = (gridDim.x * blockDim.x) >> 6;
    for (int e = wave; e < N_EDGES; e += nwaves) {
        const int src = ei[e];
        const int dst = ei[N_EDGES + e];
        const float w = ew[e];
        const float2 v = ((const float2*)(x + (size_t)src * D))[lane];
        float* op = agg + (size_t)dst * D + lane * 2;
        unsafeAtomicAdd(op,     w * v.x);
        unsafeAtomicAdd(op + 1, w * v.y);
    }
}

#define MT 32
__global__ __launch_bounds__(256, 2) void gcn_transform(
    const float* __restrict__ A, const float* __restrict__ W,
    const float* __restrict__ bias, const float* __restrict__ pa,
    float* __restrict__ out)
{
    __shared__ float Wt[D][D];
    __shared__ float xs[MT][D];
    const int tid = threadIdx.x;
    const int row0 = blockIdx.x * MT;

    for (int j = tid; j < D * (D / 4); j += 256) {
        const int n = j & 127;
        const int kg = j >> 7;
        const float4 v = ((const float4*)W)[n * (D / 4) + kg];
        const int k4 = kg << 2;
        Wt[k4 + 0][n] = v.x; Wt[k4 + 1][n] = v.y;
        Wt[k4 + 2][n] = v.z; Wt[k4 + 3][n] = v.w;
    }
    for (int i = tid; i < MT * (D / 4); i += 256) {
        const int r = i >> 5;
        const int c4 = i & 31;
        ((float4*)xs[r])[c4] = ((const float4*)(A + (size_t)(row0 + r) * D))[c4];
    }
    __syncthreads();

    const int tn = tid & 31;
    const int tm = tid >> 5;
    float acc[4][4] = {};
    #pragma unroll
    for (int k = 0; k < D; k += 4) {
        const float4 wv0 = *(const float4*)&Wt[k + 0][tn * 4];
        const float4 wv1 = *(const float4*)&Wt[k + 1][tn * 4];
        const float4 wv2 = *(const float4*)&Wt[k + 2][tn * 4];
        const float4 wv3 = *(const float4*)&Wt[k + 3][tn * 4];
        #pragma unroll
        for (int i = 0; i < 4; ++i) {
            const float4 xv = *(const float4*)&xs[tm * 4 + i][k];
            acc[i][0] += xv.x * wv0.x + xv.y * wv1.x + xv.z * wv2.x + xv.w * wv3.x;
            acc[i][1] += xv.x * wv0.y + xv.y * wv1.y + xv.z * wv2.y + xv.w * wv3.y;
            acc[i][2] += xv.x * wv0.z + xv.y * wv1.z + xv.z * wv2.z + xv.w * wv3.z;
            acc[i][3] += xv.x * wv0.w + xv.y * wv1.w + xv.z * wv2.w + xv.w * wv3.w;
        }
    }
    const float a = pa[0];
    const float4 bv = ((const float4*)bias)[tn];
    #pragma unroll
    for (int i = 0; i < 4; ++i) {
        const int gr = row0 + tm * 4 + i;
        float t0 = acc[i][0] + bv.x, t1 = acc[i][1] + bv.y;
        float t2 = acc[i][2] + bv.z, t3 = acc[i][3] + bv.w;
        float4 r;
        r.x = fmaxf(t0 >= 0.f ? t0 : a * t0, 0.f);
        r.y = fmaxf(t1 >= 0.f ? t1 : a * t1, 0.f);
        r.z = fmaxf(t2 >= 0.f ? t2 : a * t2, 0.f);
        r.w = fmaxf(t3 >= 0.f ? t3 : a * t3, 0.f);
        ((float4*)(out + (size_t)gr * D))[tn] = r;
    }
}

// ---------------------------------------------------------------------------
extern "C" void kernel_launch(void* const* d_in, const int* in_sizes, int n_in,
                              void* d_out, int out_size, void* d_ws, size_t ws_size,
                              hipStream_t stream) {
    const float* x    = (const float*)d_in[0];
    const int*   ei   = (const int*)d_in[1];
    const float* ew   = (const float*)d_in[2];
    const float* W    = (const float*)d_in[3];
    const float* bias = (const float*)d_in[4];
    const float* pa   = (const float*)d_in[5];
    float* out = (float*)d_out;

    // Workspace layout (int units)
    const size_t o_ghist = 0;
    const size_t o_cOff  = o_ghist + NCB;               // 512
    const size_t o_gcur  = o_cOff + NCB + 1;            // 1025
    const size_t o_off   = o_gcur + NCB;                // 1537
    const size_t o_part  = o_off + N_NODES + 1;         // 101538 (8B-aligned)
    const size_t o_wh    = (o_part + 2 * (size_t)N_EDGES + 3) & ~(size_t)3; // 16B-aligned
    const size_t o_xh    = o_wh + (size_t)D * D / 2;    // 16B-aligned
    const size_t endA    = o_xh + (size_t)N_NODES * D / 2;
    const size_t needA   = endA * 4;

    int* wsb = (int*)d_ws;
    int* ghist = wsb + o_ghist;
    int* cOff  = wsb + o_cOff;
    int* gcur  = wsb + o_gcur;
    int* off   = wsb + o_off;
    int2* part = (int2*)(wsb + o_part);
    unsigned short* wh = (unsigned short*)(wsb + o_wh);
    unsigned short* xh = (unsigned short*)(wsb + o_xh);

    if (ws_size >= needA) {
        (void)hipMemsetAsync(ghist, 0, NCB * sizeof(int), stream);
        k_prep <<<HB + XQB + WQB, 256, 0, stream>>>(
            (const float4*)x, (ushort4*)xh, (const float4*)W, (ushort4*)wh, ei, ghist);
        k_cscan<<<1, NCB, 0, stream>>>(ghist, cOff, gcur);
        k_part <<<(N_EDGES + CHUNK - 1) / CHUNK, 256, 0, stream>>>(ei, ew, gcur, part);
        k_csr  <<<NCB, 256, 0, stream>>>(cOff, part, off);
        k_gx   <<<N_NODES / 16, 256, 0, stream>>>(
            (const float4*)xh, off, part, wh, bias, pa, out);
    } else {
        (void)hipMemsetAsync(out, 0, (size_t)N_NODES * D * sizeof(float), stream);
        gcn_scatter<<<12800, 256, 0, stream>>>(x, ei, ew, out);
        gcn_transform<<<N_NODES / MT, 256, 0, stream>>>(out, W, bias, pa, out);
    }
}

// Round 6
// 262.629 us; speedup vs baseline: 5.6567x; 1.0528x over previous
//
#include <hip/hip_runtime.h>

#define N_NODES 100000
#define N_EDGES 1600000
#define D 128

#define NCB   512                 // coarse buckets
#define BR    196                 // nodes per coarse bucket
#define CHUNK 8192                // edges per k_part block (196 blocks = 1 round)
#define SLOTS 24                  // LDS bin capacity in k_part
#define CAP   6144                // max pairs per coarse bucket in k_csr

#define XQ   (N_NODES * D / 4)    // x float4 quads = 3,200,000
#define XQB  (XQ / 256)           // 12500 blocks (exact)
#define WQ   (D * D / 4)          // 4096
#define WQB  (WQ / 256)           // 16 blocks (exact)
#define HB   256                  // histogram blocks

typedef __bf16 bf16x8 __attribute__((ext_vector_type(8)));
typedef float  f32x4  __attribute__((ext_vector_type(4)));
typedef unsigned short u16x8 __attribute__((ext_vector_type(8)));

static __device__ __forceinline__ unsigned short f2bf(float f) {
    union { float f; unsigned u; } v; v.f = f;
    unsigned r = v.u + 0x7FFFu + ((v.u >> 16) & 1u);   // RNE
    return (unsigned short)(r >> 16);
}

// Accumulate one gathered bf16x8 row (as float4 bits) scaled by wt.
static __device__ __forceinline__ void accum_row(
    float4& acc0, float4& acc1, const float4 u, const float wt)
{
    const unsigned qx = __float_as_uint(u.x);
    const unsigned qy = __float_as_uint(u.y);
    const unsigned qz = __float_as_uint(u.z);
    const unsigned qw = __float_as_uint(u.w);
    acc0.x += wt * __uint_as_float(qx << 16);
    acc0.y += wt * __uint_as_float(qx & 0xFFFF0000u);
    acc0.z += wt * __uint_as_float(qy << 16);
    acc0.w += wt * __uint_as_float(qy & 0xFFFF0000u);
    acc1.x += wt * __uint_as_float(qz << 16);
    acc1.y += wt * __uint_as_float(qz & 0xFFFF0000u);
    acc1.z += wt * __uint_as_float(qw << 16);
    acc1.w += wt * __uint_as_float(qw & 0xFFFF0000u);
}

// ---------------------------------------------------------------------------
// k_prep: fused coarse dst histogram | x->bf16 cast | W->bf16 cast.
// Hist blocks FIRST (overlap the BW-heavy casts). Each hist block builds an
// LDS histogram then merges with 512 global atomics -> ghist is FULLY REDUCED
// when k_cscan runs.
// ---------------------------------------------------------------------------
__global__ __launch_bounds__(256) void k_prep(
    const float4* __restrict__ x4, ushort4* __restrict__ xh4,
    const float4* __restrict__ w4, ushort4* __restrict__ wh4,
    const int* __restrict__ ei, int* __restrict__ ghist)
{
    __shared__ int h[NCB];
    const int b = blockIdx.x;
    const int t = threadIdx.x;
    if (b < HB) {
        h[t] = 0; h[t + 256] = 0;
        __syncthreads();
        for (int e = b * 256 + t; e < N_EDGES; e += HB * 256)
            atomicAdd(&h[ei[N_EDGES + e] / BR], 1);
        __syncthreads();
        atomicAdd(&ghist[t], h[t]);
        atomicAdd(&ghist[t + 256], h[t + 256]);
    } else if (b < HB + XQB) {
        const int i = (b - HB) * 256 + t;
        const float4 v = x4[i];
        xh4[i] = make_ushort4(f2bf(v.x), f2bf(v.y), f2bf(v.z), f2bf(v.w));
    } else {
        const int i = (b - HB - XQB) * 256 + t;
        const float4 v = w4[i];
        wh4[i] = make_ushort4(f2bf(v.x), f2bf(v.y), f2bf(v.z), f2bf(v.w));
    }
}

// Exclusive scan of the reduced 512-entry histogram: ONE load per thread.
__global__ __launch_bounds__(512) void k_cscan(
    const int* __restrict__ ghist, int* __restrict__ cOff, int* __restrict__ gcur)
{
    __shared__ int sh[NCB];
    const int t = threadIdx.x;
    const int v = ghist[t];
    sh[t] = v;
    __syncthreads();
    for (int d = 1; d < NCB; d <<= 1) {
        int u = (t >= d) ? sh[t - d] : 0;
        __syncthreads();
        sh[t] += u;
        __syncthreads();
    }
    const int excl = sh[t] - v;
    cOff[t] = excl;
    gcur[t] = excl;
    if (t == NCB - 1) cOff[NCB] = sh[NCB - 1];
}

// ---------------------------------------------------------------------------
// Pass 1: partition edges into coarse-bucket regions with LDS binning so
// global writes land in contiguous runs. Pair packing: src | (local_dst<<17).
// CHUNK=8192 -> 196 blocks (single round at 1 block/CU).
// ---------------------------------------------------------------------------
__global__ __launch_bounds__(256, 1) void k_part(
    const int* __restrict__ ei, const float* __restrict__ ew,
    int* __restrict__ gcur, int2* __restrict__ part)
{
    __shared__ int2 bins[NCB * SLOTS];   // 96 KB
    __shared__ int bcnt[NCB];
    __shared__ int bbase[NCB];
    const int t = threadIdx.x;
    const int e0 = blockIdx.x * CHUNK;

    bcnt[t] = 0; bcnt[t + 256] = 0;
    __syncthreads();

    #pragma unroll 8
    for (int k = 0; k < CHUNK / 256; ++k) {
        const int e = e0 + k * 256 + t;
        if (e < N_EDGES) {
            const int dst = ei[N_EDGES + e];
            const int src = ei[e];
            const int b = dst / BR;
            const int ld = dst - b * BR;
            const int2 p = make_int2(src | (ld << 17), __float_as_int(ew[e]));
            const int r = atomicAdd(&bcnt[b], 1);
            if (r < SLOTS) bins[b * SLOTS + r] = p;
            else {
                int pos = atomicAdd(&gcur[b], 1);
                part[pos] = p;
            }
        }
    }
    __syncthreads();

    {
        int c0 = min(bcnt[t], SLOTS);
        int c1 = min(bcnt[t + 256], SLOTS);
        bbase[t]       = c0 ? atomicAdd(&gcur[t], c0) : 0;
        bbase[t + 256] = c1 ? atomicAdd(&gcur[t + 256], c1) : 0;
        bcnt[t] = c0; bcnt[t + 256] = c1;
    }
    __syncthreads();

    for (int s = t; s < NCB * SLOTS; s += 256) {
        const int b = s / SLOTS;
        const int r = s - b * SLOTS;
        if (r < bcnt[b]) part[bbase[b] + r] = bins[s];
    }
}

// ---------------------------------------------------------------------------
// Pass 2: per-bucket LDS sort -> in-place CSR + off[]. No obuf: reorder
// scatters directly to global (region is L2-hot; all reads complete before
// the barrier). LDS 51 KB -> 3 blocks/CU.
// ---------------------------------------------------------------------------
__global__ __launch_bounds__(256) void k_csr(
    const int* __restrict__ cOff, int2* __restrict__ part, int* __restrict__ off)
{
    __shared__ int2 buf[CAP];    // 48 KB
    __shared__ int nh[256];
    __shared__ int orig[256];
    __shared__ int cur[256];

    const int b = blockIdx.x;
    const int t = threadIdx.x;
    const int lo = b * BR;
    const int base = cOff[b];
    int cnt = cOff[b + 1] - base;
    if (cnt > CAP) cnt = CAP;    // unreachable statistically; guards LDS

    nh[t] = 0;
    __syncthreads();

    for (int i = t; i < cnt; i += 256) {
        const int2 p = part[base + i];
        buf[i] = p;
        atomicAdd(&nh[((unsigned)p.x) >> 17], 1);
    }
    __syncthreads();
    orig[t] = nh[t];
    __syncthreads();
    for (int d = 1; d < 256; d <<= 1) {
        int u = (t >= d) ? nh[t - d] : 0;
        __syncthreads();
        nh[t] += u;
        __syncthreads();
    }
    const int excl = nh[t] - orig[t];
    cur[t] = excl;
    if (t < BR && lo + t < N_NODES) off[lo + t] = base + excl;
    if (b == NCB - 1 && t == 0) off[N_NODES] = cOff[NCB];
    __syncthreads();

    for (int i = t; i < cnt; i += 256) {
        const int2 p = buf[i];
        const int ld = ((unsigned)p.x) >> 17;
        const int r = atomicAdd(&cur[ld], 1);
        part[base + r] = make_int2(p.x & 0x1FFFF, p.y);
    }
}

// ---------------------------------------------------------------------------
// Fused gather + MFMA transform: out = relu(prelu((A x)_tile @ W^T + b, a)).
// RESTRUCTURED: 256 threads = 16 groups of 16 lanes; group g exclusively owns
// node m0+g. All 16 nodes of the tile progress CONCURRENTLY (the old version
// walked 4 nodes serially per wave). Per edge: 16 lanes x 16B = the full
// 256B row in one issue slot; pair reads are broadcast loads from the group's
// contiguous CSR run (32B per 4 edges, L1-hot). 4-deep unroll = 4 rows in
// flight per group = 64 per block. NO shuffle folds: each lane owns feature
// chunk 8*sl end-to-end and writes it straight to the LDS tile.
// Then the unchanged 16x16x32 MFMA transform (2 n-tiles per wave).
// Layouts (verified m89/m91): A[m=lane&15][k=quad*8+j], B[n=lane&15][k=...],
// C: col=lane&15, row=quad*4+reg.
// ---------------------------------------------------------------------------
__global__ __launch_bounds__(256) void k_gx(
    const float4* __restrict__ xh4,        // bf16 x rows viewed as float4 (8 bf16)
    const int* __restrict__ off,
    const int2* __restrict__ pair,         // CSR {src, w}
    const unsigned short* __restrict__ wh, // bf16 W [n][k]
    const float* __restrict__ bias, const float* __restrict__ pa,
    float* __restrict__ out)
{
    __shared__ unsigned short tb[16][136]; // bf16 tile, stride 272B

    const int tid = threadIdx.x;
    const int g   = tid >> 4;              // 0..15: which node of the tile
    const int sl  = tid & 15;              // feature chunk: 8 bf16 at 8*sl
    const int m0  = blockIdx.x << 4;
    const float aP = pa[0];

    // ---- gather: group g streams node (m0+g)'s edge list ----
    {
        const int n = m0 + g;
        const int beg = off[n], end = off[n + 1];
        float4 acc0 = make_float4(0.f, 0.f, 0.f, 0.f);
        float4 acc1 = make_float4(0.f, 0.f, 0.f, 0.f);

        int e = beg;
        for (; e + 3 < end; e += 4) {
            const int2 p0 = pair[e + 0], p1 = pair[e + 1];
            const int2 p2 = pair[e + 2], p3 = pair[e + 3];
            const float4 u0 = xh4[p0.x * 16 + sl];
            const float4 u1 = xh4[p1.x * 16 + sl];
            const float4 u2 = xh4[p2.x * 16 + sl];
            const float4 u3 = xh4[p3.x * 16 + sl];
            accum_row(acc0, acc1, u0, __int_as_float(p0.y));
            accum_row(acc0, acc1, u1, __int_as_float(p1.y));
            accum_row(acc0, acc1, u2, __int_as_float(p2.y));
            accum_row(acc0, acc1, u3, __int_as_float(p3.y));
        }
        for (; e < end; ++e) {
            const int2 p = pair[e];
            const float4 u = xh4[p.x * 16 + sl];
            accum_row(acc0, acc1, u, __int_as_float(p.y));
        }

        u16x8 s;
        s[0] = f2bf(acc0.x); s[1] = f2bf(acc0.y);
        s[2] = f2bf(acc0.z); s[3] = f2bf(acc0.w);
        s[4] = f2bf(acc1.x); s[5] = f2bf(acc1.y);
        s[6] = f2bf(acc1.z); s[7] = f2bf(acc1.w);
        *(u16x8*)&tb[g][sl * 8] = s;       // features 8sl..8sl+7, 16B aligned
    }
    __syncthreads();

    // ---- MFMA transform on the 16-row bf16 tile ----
    const int lane = tid & 63;
    const int wv = tid >> 6;
    const int mm = lane & 15;
    const int quad = lane >> 4;

    bf16x8 af[4];
    #pragma unroll
    for (int c = 0; c < 4; ++c)
        af[c] = *(const bf16x8*)&tb[mm][c * 32 + quad * 8];

    #pragma unroll
    for (int t = 0; t < 2; ++t) {
        const int n = ((wv * 2 + t) << 4) + mm;
        f32x4 acc = {0.f, 0.f, 0.f, 0.f};
        #pragma unroll
        for (int c = 0; c < 4; ++c) {
            const bf16x8 bf = *(const bf16x8*)(wh + n * D + c * 32 + quad * 8);
            acc = __builtin_amdgcn_mfma_f32_16x16x32_bf16(af[c], bf, acc, 0, 0, 0);
        }
        const float bv = bias[n];
        #pragma unroll
        for (int r = 0; r < 4; ++r) {
            float v = acc[r] + bv;
            v = (v >= 0.f) ? v : aP * v;
            v = fmaxf(v, 0.f);
            out[(size_t)(m0 + (quad << 2) + r) * D + n] = v;
        }
    }
}

// ---------------------------------------------------------------------------
// Tier-C fallbacks (tiny ws): atomic scatter + fp32 vector transform.
// ---------------------------------------------------------------------------
__global__ __launch_bounds__(256) void gcn_scatter(
    const float* __restrict__ x, const int* __restrict__ ei,
    const float* __restrict__ ew, float* __restrict__ agg)
{
    const int lane = threadIdx.x & 63;
    const int wave = (blockIdx.x * blockDim.x + threadIdx.x) >> 6;
    const int nwaves = (gridDim.x * blockDim.x) >> 6;
    for (int e = wave; e < N_EDGES; e += nwaves) {
        const int src = ei[e];
        const int dst = ei[N_EDGES + e];
        const float w = ew[e];
        const float2 v = ((const float2*)(x + (size_t)src * D))[lane];
        float* op = agg + (size_t)dst * D + lane * 2;
        unsafeAtomicAdd(op,     w * v.x);
        unsafeAtomicAdd(op + 1, w * v.y);
    }
}

#define MT 32
__global__ __launch_bounds__(256, 2) void gcn_transform(
    const float* __restrict__ A, const float* __restrict__ W,
    const float* __restrict__ bias, const float* __restrict__ pa,
    float* __restrict__ out)
{
    __shared__ float Wt[D][D];
    __shared__ float xs[MT][D];
    const int tid = threadIdx.x;
    const int row0 = blockIdx.x * MT;

    for (int j = tid; j < D * (D / 4); j += 256) {
        const int n = j & 127;
        const int kg = j >> 7;
        const float4 v = ((const float4*)W)[n * (D / 4) + kg];
        const int k4 = kg << 2;
        Wt[k4 + 0][n] = v.x; Wt[k4 + 1][n] = v.y;
        Wt[k4 + 2][n] = v.z; Wt[k4 + 3][n] = v.w;
    }
    for (int i = tid; i < MT * (D / 4); i += 256) {
        const int r = i >> 5;
        const int c4 = i & 31;
        ((float4*)xs[r])[c4] = ((const float4*)(A + (size_t)(row0 + r) * D))[c4];
    }
    __syncthreads();

    const int tn = tid & 31;
    const int tm = tid >> 5;
    float acc[4][4] = {};
    #pragma unroll
    for (int k = 0; k < D; k += 4) {
        const float4 wv0 = *(const float4*)&Wt[k + 0][tn * 4];
        const float4 wv1 = *(const float4*)&Wt[k + 1][tn * 4];
        const float4 wv2 = *(const float4*)&Wt[k + 2][tn * 4];
        const float4 wv3 = *(const float4*)&Wt[k + 3][tn * 4];
        #pragma unroll
        for (int i = 0; i < 4; ++i) {
            const float4 xv = *(const float4*)&xs[tm * 4 + i][k];
            acc[i][0] += xv.x * wv0.x + xv.y * wv1.x + xv.z * wv2.x + xv.w * wv3.x;
            acc[i][1] += xv.x * wv0.y + xv.y * wv1.y + xv.z * wv2.y + xv.w * wv3.y;
            acc[i][2] += xv.x * wv0.z + xv.y * wv1.z + xv.z * wv2.z + xv.w * wv3.z;
            acc[i][3] += xv.x * wv0.w + xv.y * wv1.w + xv.z * wv2.w + xv.w * wv3.w;
        }
    }
    const float a = pa[0];
    const float4 bv = ((const float4*)bias)[tn];
    #pragma unroll
    for (int i = 0; i < 4; ++i) {
        const int gr = row0 + tm * 4 + i;
        float t0 = acc[i][0] + bv.x, t1 = acc[i][1] + bv.y;
        float t2 = acc[i][2] + bv.z, t3 = acc[i][3] + bv.w;
        float4 r;
        r.x = fmaxf(t0 >= 0.f ? t0 : a * t0, 0.f);
        r.y = fmaxf(t1 >= 0.f ? t1 : a * t1, 0.f);
        r.z = fmaxf(t2 >= 0.f ? t2 : a * t2, 0.f);
        r.w = fmaxf(t3 >= 0.f ? t3 : a * t3, 0.f);
        ((float4*)(out + (size_t)gr * D))[tn] = r;
    }
}

// ---------------------------------------------------------------------------
extern "C" void kernel_launch(void* const* d_in, const int* in_sizes, int n_in,
                              void* d_out, int out_size, void* d_ws, size_t ws_size,
                              hipStream_t stream) {
    const float* x    = (const float*)d_in[0];
    const int*   ei   = (const int*)d_in[1];
    const float* ew   = (const float*)d_in[2];
    const float* W    = (const float*)d_in[3];
    const float* bias = (const float*)d_in[4];
    const float* pa   = (const float*)d_in[5];
    float* out = (float*)d_out;

    // Workspace layout (int units)
    const size_t o_ghist = 0;
    const size_t o_cOff  = o_ghist + NCB;               // 512
    const size_t o_gcur  = o_cOff + NCB + 1;            // 1025
    const size_t o_off   = o_gcur + NCB;                // 1537
    const size_t o_part  = o_off + N_NODES + 1;         // 101538 (8B-aligned)
    const size_t o_wh    = (o_part + 2 * (size_t)N_EDGES + 3) & ~(size_t)3; // 16B-aligned
    const size_t o_xh    = o_wh + (size_t)D * D / 2;    // 16B-aligned
    const size_t endA    = o_xh + (size_t)N_NODES * D / 2;
    const size_t needA   = endA * 4;

    int* wsb = (int*)d_ws;
    int* ghist = wsb + o_ghist;
    int* cOff  = wsb + o_cOff;
    int* gcur  = wsb + o_gcur;
    int* off   = wsb + o_off;
    int2* part = (int2*)(wsb + o_part);
    unsigned short* wh = (unsigned short*)(wsb + o_wh);
    unsigned short* xh = (unsigned short*)(wsb + o_xh);

    if (ws_size >= needA) {
        (void)hipMemsetAsync(ghist, 0, NCB * sizeof(int), stream);
        k_prep <<<HB + XQB + WQB, 256, 0, stream>>>(
            (const float4*)x, (ushort4*)xh, (const float4*)W, (ushort4*)wh, ei, ghist);
        k_cscan<<<1, NCB, 0, stream>>>(ghist, cOff, gcur);
        k_part <<<(N_EDGES + CHUNK - 1) / CHUNK, 256, 0, stream>>>(ei, ew, gcur, part);
        k_csr  <<<NCB, 256, 0, stream>>>(cOff, part, off);
        k_gx   <<<N_NODES / 16, 256, 0, stream>>>(
            (const float4*)xh, off, part, wh, bias, pa, out);
    } else {
        (void)hipMemsetAsync(out, 0, (size_t)N_NODES * D * sizeof(float), stream);
        gcn_scatter<<<12800, 256, 0, stream>>>(x, ei, ew, out);
        gcn_transform<<<N_NODES / MT, 256, 0, stream>>>(out, W, bias, pa, out);
    }
}